// Round 2
// baseline (394.268 us; speedup 1.0000x reference)
//
#include <hip/hip_runtime.h>
#include <hip/hip_bf16.h>

typedef unsigned short u16;
typedef unsigned int u32;
typedef __bf16 bf16x8 __attribute__((ext_vector_type(8)));
typedef float f32x4 __attribute__((ext_vector_type(4)));

#define NN 50000
#define NE 640000
#define DH 128
#define NTILES (NN / 16)   // 3125, exact

__device__ __forceinline__ u16 f2bf(float f) {
  u32 i = __float_as_uint(f);
  u32 r = (i + 0x7FFFu + ((i >> 16) & 1u)) >> 16;   // RNE
  return (u16)r;
}
__device__ __forceinline__ float bflo(u32 v) { return __uint_as_float(v << 16); }
__device__ __forceinline__ float bfhi(u32 v) { return __uint_as_float(v & 0xFFFF0000u); }

// ---------------- cast x + all weights fp32 -> bf16 (one launch) --------------
// wb layout (elements): pre_w@0, wl0@16384, wr0@32768, wl1@49152, wr1@65536, lin_w@81920 (total 114688)
__global__ void cast_all(const float* __restrict__ x,
                         const float* __restrict__ pw, const float* __restrict__ wl0,
                         const float* __restrict__ wr0, const float* __restrict__ wl1,
                         const float* __restrict__ wr1, const float* __restrict__ lw,
                         u16* __restrict__ xb, u16* __restrict__ wb) {
  int idx = blockIdx.x * blockDim.x + threadIdx.x;
  long i4 = (long)idx * 4;
  const long XCNT = (long)NN * DH;      // 6,400,000
  const long WCNT = 114688;
  if (i4 < XCNT) {
    float4 v = *(const float4*)(x + i4);
    u32 a = (u32)f2bf(v.x) | ((u32)f2bf(v.y) << 16);
    u32 b = (u32)f2bf(v.z) | ((u32)f2bf(v.w) << 16);
    uint2 o = make_uint2(a, b);
    *(uint2*)(xb + i4) = o;
  } else if (i4 < XCNT + WCNT) {
    long w = i4 - XCNT;
    const float* src; long off;
    if (w < 16384)      { src = pw;  off = 0; }
    else if (w < 32768) { src = wl0; off = 16384; }
    else if (w < 49152) { src = wr0; off = 32768; }
    else if (w < 65536) { src = wl1; off = 49152; }
    else if (w < 81920) { src = wr1; off = 65536; }
    else                { src = lw;  off = 81920; }
    float4 v = *(const float4*)(src + (w - off));
    u32 a = (u32)f2bf(v.x) | ((u32)f2bf(v.y) << 16);
    u32 b = (u32)f2bf(v.z) | ((u32)f2bf(v.w) << 16);
    *(uint2*)(wb + w) = make_uint2(a, b);
  }
}

// ---------------- CSR build ----------------
__global__ void count_kernel(const int* __restrict__ ei, int* __restrict__ cnt) {
  int e = blockIdx.x * blockDim.x + threadIdx.x;
  if (e < NE) atomicAdd(&cnt[ei[NE + e]], 1);
}

__global__ __launch_bounds__(1024) void scan_kernel(const int* __restrict__ cnt,
                                                    int* __restrict__ off,
                                                    int* __restrict__ fillpos) {
  __shared__ int sm[1024];
  int tid = threadIdx.x;
  const int per = (NN + 1023) / 1024;   // 49
  int s = tid * per;
  int e = s + per; if (e > NN) e = NN; if (s > NN) s = NN;
  int local = 0;
  for (int i = s; i < e; ++i) local += cnt[i];
  sm[tid] = local;
  __syncthreads();
  for (int d = 1; d < 1024; d <<= 1) {
    int t = (tid >= d) ? sm[tid - d] : 0;
    __syncthreads();
    sm[tid] += t;
    __syncthreads();
  }
  int run = sm[tid] - local;   // exclusive prefix
  for (int i = s; i < e; ++i) { off[i] = run; fillpos[i] = run; run += cnt[i]; }
  if (tid == 1023) off[NN] = run;
}

__global__ void fill_kernel(const int* __restrict__ ei, int* __restrict__ fillpos,
                            int* __restrict__ srcs) {
  int e = blockIdx.x * blockDim.x + threadIdx.x;
  if (e < NE) {
    int d = ei[NE + e];
    int p = atomicAdd(&fillpos[d], 1);
    srcs[p] = ei[e];
  }
}

// ---------------- mean aggregation: agg[i] = mean_{e: dst=i} h[src[e]] --------
// one wave per node; 4 edges in flight (16 lanes x 16B each)
__global__ __launch_bounds__(256) void agg_kernel(const u16* __restrict__ h,
                                                  const int* __restrict__ off,
                                                  const int* __restrict__ srcs,
                                                  u16* __restrict__ agg) {
  int node = blockIdx.x * 4 + (threadIdx.x >> 6);
  int lane = threadIdx.x & 63;
  int sub = lane >> 4;        // 0..3: which edge of the quad
  int c16 = lane & 15;        // which 16B chunk of the row
  int e0 = off[node], e1 = off[node + 1];
  float a0=0,a1=0,a2=0,a3=0,a4=0,a5=0,a6=0,a7=0;
  for (int e = e0 + sub; e < e1; e += 4) {
    int s = srcs[e];
    uint4 v = *(const uint4*)(h + (size_t)s * DH + c16 * 8);
    a0 += bflo(v.x); a1 += bfhi(v.x);
    a2 += bflo(v.y); a3 += bfhi(v.y);
    a4 += bflo(v.z); a5 += bfhi(v.z);
    a6 += bflo(v.w); a7 += bfhi(v.w);
  }
  // combine the 4 edge-subgroups (lanes differing in bits 4,5)
  a0 += __shfl_xor(a0,16); a0 += __shfl_xor(a0,32);
  a1 += __shfl_xor(a1,16); a1 += __shfl_xor(a1,32);
  a2 += __shfl_xor(a2,16); a2 += __shfl_xor(a2,32);
  a3 += __shfl_xor(a3,16); a3 += __shfl_xor(a3,32);
  a4 += __shfl_xor(a4,16); a4 += __shfl_xor(a4,32);
  a5 += __shfl_xor(a5,16); a5 += __shfl_xor(a5,32);
  a6 += __shfl_xor(a6,16); a6 += __shfl_xor(a6,32);
  a7 += __shfl_xor(a7,16); a7 += __shfl_xor(a7,32);
  int deg = e1 - e0;
  float inv = 1.0f / (float)(deg > 0 ? deg : 1);
  if (sub == 0) {
    uint4 o;
    o.x = (u32)f2bf(a0 * inv) | ((u32)f2bf(a1 * inv) << 16);
    o.y = (u32)f2bf(a2 * inv) | ((u32)f2bf(a3 * inv) << 16);
    o.z = (u32)f2bf(a4 * inv) | ((u32)f2bf(a5 * inv) << 16);
    o.w = (u32)f2bf(a6 * inv) | ((u32)f2bf(a7 * inv) << 16);
    *(uint4*)(agg + (size_t)node * DH + c16 * 8) = o;
  }
}

// ---------------- fused GEMM (+optional second input) + bias + LN + ReLU ------
// out[n][j] = relu(LN_j(sum_k A1[n][k]W1[j][k] (+ A2[n][k]W2[j][k]) + bias[j]))
// A,W bf16 row-major [.,128]; out bf16 [NN][128]
__global__ __launch_bounds__(256) void gemm_ln_relu(const u16* __restrict__ A1,
                                                    const u16* __restrict__ W1,
                                                    const u16* __restrict__ A2,
                                                    const u16* __restrict__ W2,
                                                    const float* __restrict__ bias,
                                                    const float* __restrict__ g,
                                                    const float* __restrict__ be,
                                                    u16* __restrict__ outh) {
  int lane = threadIdx.x & 63;
  int ntile = blockIdx.x * 4 + (threadIdx.x >> 6);
  if (ntile >= NTILES) return;
  int rA = lane & 15;       // A row within tile
  int ksel = lane >> 4;     // k sub-block 0..3
  int nodeA = ntile * 16 + rA;

  f32x4 acc[8];
  #pragma unroll
  for (int j = 0; j < 8; ++j) acc[j] = (f32x4){0.f,0.f,0.f,0.f};

  for (int pass = 0; pass < 2; ++pass) {
    const u16* A = pass ? A2 : A1;
    const u16* W = pass ? W2 : W1;
    if (!A) break;
    const u16* arow = A + (size_t)nodeA * DH + ksel * 8;
    const u16* wrow = W + (size_t)rA * DH + ksel * 8;
    #pragma unroll
    for (int ks = 0; ks < 4; ++ks) {
      bf16x8 af = *(const bf16x8*)(arow + ks * 32);
      #pragma unroll
      for (int jt = 0; jt < 8; ++jt) {
        bf16x8 bf = *(const bf16x8*)(wrow + ks * 32 + jt * 16 * DH);
        acc[jt] = __builtin_amdgcn_mfma_f32_16x16x32_bf16(af, bf, acc[jt], 0, 0, 0);
      }
    }
  }

  // epilogue: D[row=(lane>>4)*4+r][col=lane&15]
  int jcol = lane & 15;
  int rbase = (lane >> 4) * 4;
  float gv[8], bev[8];
  #pragma unroll
  for (int jt = 0; jt < 8; ++jt) {
    int j = jt * 16 + jcol;
    float bi = bias[j];
    gv[jt] = g[j]; bev[jt] = be[j];
    #pragma unroll
    for (int r = 0; r < 4; ++r) acc[jt][r] += bi;
  }
  #pragma unroll
  for (int r = 0; r < 4; ++r) {
    float s = 0.f;
    #pragma unroll
    for (int jt = 0; jt < 8; ++jt) s += acc[jt][r];
    s += __shfl_xor(s, 1); s += __shfl_xor(s, 2);
    s += __shfl_xor(s, 4); s += __shfl_xor(s, 8);
    float mean = s * (1.0f / 128.0f);
    float q = 0.f;
    #pragma unroll
    for (int jt = 0; jt < 8; ++jt) { float d = acc[jt][r] - mean; q += d * d; }
    q += __shfl_xor(q, 1); q += __shfl_xor(q, 2);
    q += __shfl_xor(q, 4); q += __shfl_xor(q, 8);
    float rs = rsqrtf(q * (1.0f / 128.0f) + 1e-5f);
    int node = ntile * 16 + rbase + r;
    u16* orow = outh + (size_t)node * DH + jcol;
    #pragma unroll
    for (int jt = 0; jt < 8; ++jt) {
      float y = (acc[jt][r] - mean) * rs * gv[jt] + bev[jt];
      y = fmaxf(y, 0.f);
      orow[jt * 16] = f2bf(y);
    }
  }
}

// ---------------- final linear: out[n][128+j] = h@lin_w.T + lin_b (fp32) ------
__global__ __launch_bounds__(256) void final_kernel(const u16* __restrict__ A,
                                                    const u16* __restrict__ W,
                                                    const float* __restrict__ bias,
                                                    float* __restrict__ out) {
  int lane = threadIdx.x & 63;
  int ntile = blockIdx.x * 4 + (threadIdx.x >> 6);
  if (ntile >= NTILES) return;
  int rA = lane & 15;
  int ksel = lane >> 4;
  int nodeA = ntile * 16 + rA;

  f32x4 acc[16];
  #pragma unroll
  for (int j = 0; j < 16; ++j) acc[j] = (f32x4){0.f,0.f,0.f,0.f};

  const u16* arow = A + (size_t)nodeA * DH + ksel * 8;
  const u16* wrow = W + (size_t)rA * DH + ksel * 8;
  #pragma unroll
  for (int ks = 0; ks < 4; ++ks) {
    bf16x8 af = *(const bf16x8*)(arow + ks * 32);
    #pragma unroll
    for (int jt = 0; jt < 16; ++jt) {
      bf16x8 bf = *(const bf16x8*)(wrow + ks * 32 + jt * 16 * DH);
      acc[jt] = __builtin_amdgcn_mfma_f32_16x16x32_bf16(af, bf, acc[jt], 0, 0, 0);
    }
  }

  int jcol = lane & 15;
  int rbase = (lane >> 4) * 4;
  float bv[16];
  #pragma unroll
  for (int jt = 0; jt < 16; ++jt) bv[jt] = bias[jt * 16 + jcol];
  #pragma unroll
  for (int r = 0; r < 4; ++r) {
    int node = ntile * 16 + rbase + r;
    float* orow = out + (size_t)node * 384 + 128 + jcol;
    #pragma unroll
    for (int jt = 0; jt < 16; ++jt) orow[jt * 16] = acc[jt][r] + bv[jt];
  }
}

// ---------------- copy raw x into out[:, 0:128] ----------------
__global__ void copy_x(const float* __restrict__ x, float* __restrict__ out) {
  int idx = blockIdx.x * blockDim.x + threadIdx.x;   // one float4 each
  int n = idx >> 5;          // 32 float4 per row
  int c = idx & 31;
  if (n < NN)
    *(float4*)(out + (size_t)n * 384 + c * 4) = *(const float4*)(x + (size_t)n * DH + c * 4);
}

extern "C" void kernel_launch(void* const* d_in, const int* in_sizes, int n_in,
                              void* d_out, int out_size, void* d_ws, size_t ws_size,
                              hipStream_t stream) {
  const float* x      = (const float*)d_in[0];
  const int*   ei     = (const int*)d_in[1];
  const float* pre_w  = (const float*)d_in[2];
  const float* pre_b  = (const float*)d_in[3];
  const float* pre_g  = (const float*)d_in[4];
  const float* pre_be = (const float*)d_in[5];
  const float* wl0    = (const float*)d_in[6];
  const float* wr0    = (const float*)d_in[7];
  const float* b0     = (const float*)d_in[8];
  const float* g0     = (const float*)d_in[9];
  const float* be0    = (const float*)d_in[10];
  const float* wl1    = (const float*)d_in[11];
  const float* wr1    = (const float*)d_in[12];
  const float* b1     = (const float*)d_in[13];
  const float* g1     = (const float*)d_in[14];
  const float* be1    = (const float*)d_in[15];
  const float* lin_w  = (const float*)d_in[16];
  const float* lin_b  = (const float*)d_in[17];
  float* out = (float*)d_out;

  char* ws = (char*)d_ws;
  size_t o = 0;
  auto alloc = [&](size_t bytes) { void* p = ws + o; o += (bytes + 255) & ~255ULL; return p; };
  u16* xb   = (u16*)alloc((size_t)NN * DH * 2);
  u16* hA   = (u16*)alloc((size_t)NN * DH * 2);
  u16* hB   = (u16*)alloc((size_t)NN * DH * 2);
  u16* aggb = (u16*)alloc((size_t)NN * DH * 2);
  u16* wb   = (u16*)alloc((size_t)114688 * 2);
  int* cnt     = (int*)alloc((size_t)NN * 4);
  int* off     = (int*)alloc((size_t)(NN + 1) * 4);
  int* fillpos = (int*)alloc((size_t)NN * 4);
  int* srcs    = (int*)alloc((size_t)NE * 4);

  hipMemsetAsync(cnt, 0, (size_t)NN * 4, stream);

  {
    long total4 = ((long)NN * DH + 114688) / 4;
    int blocks = (int)((total4 + 255) / 256);
    cast_all<<<blocks, 256, 0, stream>>>(x, pre_w, wl0, wr0, wl1, wr1, lin_w, xb, wb);
  }
  count_kernel<<<NE / 256, 256, 0, stream>>>(ei, cnt);
  scan_kernel<<<1, 1024, 0, stream>>>(cnt, off, fillpos);
  fill_kernel<<<NE / 256, 256, 0, stream>>>(ei, fillpos, srcs);

  int gblocks = (NTILES + 3) / 4;   // 782
  // pre-MP layer
  gemm_ln_relu<<<gblocks, 256, 0, stream>>>(xb, wb + 0, nullptr, nullptr,
                                            pre_b, pre_g, pre_be, hA);
  // SAGE layer 0
  agg_kernel<<<NN / 4, 256, 0, stream>>>(hA, off, srcs, aggb);
  gemm_ln_relu<<<gblocks, 256, 0, stream>>>(aggb, wb + 16384, hA, wb + 32768,
                                            b0, g0, be0, hB);
  // SAGE layer 1
  agg_kernel<<<NN / 4, 256, 0, stream>>>(hB, off, srcs, aggb);
  gemm_ln_relu<<<gblocks, 256, 0, stream>>>(aggb, wb + 49152, hB, wb + 65536,
                                            b1, g1, be1, hA);
  // output
  copy_x<<<(NN * 32) / 256, 256, 0, stream>>>(x, out);
  final_kernel<<<gblocks, 256, 0, stream>>>(hA, wb + 81920, lin_b, out);
}

// Round 3
// 295.914 us; speedup vs baseline: 1.3324x; 1.3324x over previous
//
#include <hip/hip_runtime.h>
#include <hip/hip_bf16.h>

typedef unsigned short u16;
typedef unsigned int u32;
typedef __bf16 bf16x8 __attribute__((ext_vector_type(8)));
typedef float f32x4 __attribute__((ext_vector_type(4)));

#define NN 50000
#define NE 640000
#define DH 128
#define NTILES (NN / 16)        // 3125, exact
#define NBLK ((NN + 255) / 256) // 196 scan blocks

__device__ __forceinline__ u16 f2bf(float f) {
  u32 i = __float_as_uint(f);
  u32 r = (i + 0x7FFFu + ((i >> 16) & 1u)) >> 16;   // RNE
  return (u16)r;
}
__device__ __forceinline__ float bflo(u32 v) { return __uint_as_float(v << 16); }
__device__ __forceinline__ float bfhi(u32 v) { return __uint_as_float(v & 0xFFFF0000u); }

// ---------------- cast x + all weights fp32 -> bf16 (one launch) --------------
// wb layout (elements): pre_w@0, wl0@16384, wr0@32768, wl1@49152, wr1@65536, lin_w@81920
__global__ void cast_all(const float* __restrict__ x,
                         const float* __restrict__ pw, const float* __restrict__ wl0,
                         const float* __restrict__ wr0, const float* __restrict__ wl1,
                         const float* __restrict__ wr1, const float* __restrict__ lw,
                         u16* __restrict__ xb, u16* __restrict__ wb) {
  int idx = blockIdx.x * blockDim.x + threadIdx.x;
  long i4 = (long)idx * 4;
  const long XCNT = (long)NN * DH;      // 6,400,000
  const long WCNT = 114688;
  if (i4 < XCNT) {
    float4 v = *(const float4*)(x + i4);
    u32 a = (u32)f2bf(v.x) | ((u32)f2bf(v.y) << 16);
    u32 b = (u32)f2bf(v.z) | ((u32)f2bf(v.w) << 16);
    *(uint2*)(xb + i4) = make_uint2(a, b);
  } else if (i4 < XCNT + WCNT) {
    long w = i4 - XCNT;
    const float* src; long off;
    if (w < 16384)      { src = pw;  off = 0; }
    else if (w < 32768) { src = wl0; off = 16384; }
    else if (w < 49152) { src = wr0; off = 32768; }
    else if (w < 65536) { src = wl1; off = 49152; }
    else if (w < 81920) { src = wr1; off = 65536; }
    else                { src = lw;  off = 81920; }
    float4 v = *(const float4*)(src + (w - off));
    u32 a = (u32)f2bf(v.x) | ((u32)f2bf(v.y) << 16);
    u32 b = (u32)f2bf(v.z) | ((u32)f2bf(v.w) << 16);
    *(uint2*)(wb + w) = make_uint2(a, b);
  }
}

// ---------------- CSR build ----------------
__global__ void count_kernel(const int* __restrict__ ei, int* __restrict__ cnt) {
  int e = blockIdx.x * blockDim.x + threadIdx.x;
  if (e < NE) atomicAdd(&cnt[ei[NE + e]], 1);
}

// hierarchical scan, stage 1: per-block (256 counts) totals
__global__ __launch_bounds__(256) void scan_part(const int* __restrict__ cnt,
                                                 int* __restrict__ partial) {
  __shared__ int sm[4];
  int i = blockIdx.x * 256 + threadIdx.x;
  int s = (i < NN) ? cnt[i] : 0;
  s += __shfl_xor(s, 1);  s += __shfl_xor(s, 2);  s += __shfl_xor(s, 4);
  s += __shfl_xor(s, 8);  s += __shfl_xor(s, 16); s += __shfl_xor(s, 32);
  if ((threadIdx.x & 63) == 0) sm[threadIdx.x >> 6] = s;
  __syncthreads();
  if (threadIdx.x == 0) partial[blockIdx.x] = sm[0] + sm[1] + sm[2] + sm[3];
}

// stage 2: exclusive scan of NBLK (<=256) partials, in place
__global__ __launch_bounds__(256) void scan_top(int* __restrict__ partial) {
  __shared__ int sm[256];
  int tid = threadIdx.x;
  int v = (tid < NBLK) ? partial[tid] : 0;
  sm[tid] = v;
  __syncthreads();
  for (int d = 1; d < 256; d <<= 1) {
    int t = (tid >= d) ? sm[tid - d] : 0;
    __syncthreads();
    sm[tid] += t;
    __syncthreads();
  }
  if (tid < NBLK) partial[tid] = sm[tid] - v;   // exclusive prefix
}

// stage 3: per-block scan + global offset, write off/fillpos
__global__ __launch_bounds__(256) void scan_final(const int* __restrict__ cnt,
                                                  const int* __restrict__ partial,
                                                  int* __restrict__ off,
                                                  int* __restrict__ fillpos) {
  __shared__ int sm[256];
  int tid = threadIdx.x;
  int i = blockIdx.x * 256 + tid;
  int v = (i < NN) ? cnt[i] : 0;
  sm[tid] = v;
  __syncthreads();
  for (int d = 1; d < 256; d <<= 1) {
    int t = (tid >= d) ? sm[tid - d] : 0;
    __syncthreads();
    sm[tid] += t;
    __syncthreads();
  }
  int excl = sm[tid] - v + partial[blockIdx.x];
  if (i < NN) { off[i] = excl; fillpos[i] = excl; }
  if (i == 0) off[NN] = NE;   // total edges is a constant
}

__global__ void fill_kernel(const int* __restrict__ ei, int* __restrict__ fillpos,
                            int* __restrict__ srcs) {
  int e = blockIdx.x * blockDim.x + threadIdx.x;
  if (e < NE) {
    int d = ei[NE + e];
    int p = atomicAdd(&fillpos[d], 1);
    srcs[p] = ei[e];
  }
}

// ---------------- mean aggregation: agg[i] = mean_{e: dst=i} h[src[e]] --------
// one wave per node; 4 edges in flight (16 lanes x 16B each)
__global__ __launch_bounds__(256) void agg_kernel(const u16* __restrict__ h,
                                                  const int* __restrict__ off,
                                                  const int* __restrict__ srcs,
                                                  u16* __restrict__ agg) {
  int node = blockIdx.x * 4 + (threadIdx.x >> 6);
  int lane = threadIdx.x & 63;
  int sub = lane >> 4;        // 0..3: which edge of the quad
  int c16 = lane & 15;        // which 16B chunk of the row
  int e0 = off[node], e1 = off[node + 1];
  float a0=0,a1=0,a2=0,a3=0,a4=0,a5=0,a6=0,a7=0;
  for (int e = e0 + sub; e < e1; e += 4) {
    int s = srcs[e];
    uint4 v = *(const uint4*)(h + (size_t)s * DH + c16 * 8);
    a0 += bflo(v.x); a1 += bfhi(v.x);
    a2 += bflo(v.y); a3 += bfhi(v.y);
    a4 += bflo(v.z); a5 += bfhi(v.z);
    a6 += bflo(v.w); a7 += bfhi(v.w);
  }
  a0 += __shfl_xor(a0,16); a0 += __shfl_xor(a0,32);
  a1 += __shfl_xor(a1,16); a1 += __shfl_xor(a1,32);
  a2 += __shfl_xor(a2,16); a2 += __shfl_xor(a2,32);
  a3 += __shfl_xor(a3,16); a3 += __shfl_xor(a3,32);
  a4 += __shfl_xor(a4,16); a4 += __shfl_xor(a4,32);
  a5 += __shfl_xor(a5,16); a5 += __shfl_xor(a5,32);
  a6 += __shfl_xor(a6,16); a6 += __shfl_xor(a6,32);
  a7 += __shfl_xor(a7,16); a7 += __shfl_xor(a7,32);
  int deg = e1 - e0;
  float inv = 1.0f / (float)(deg > 0 ? deg : 1);
  if (sub == 0) {
    uint4 o;
    o.x = (u32)f2bf(a0 * inv) | ((u32)f2bf(a1 * inv) << 16);
    o.y = (u32)f2bf(a2 * inv) | ((u32)f2bf(a3 * inv) << 16);
    o.z = (u32)f2bf(a4 * inv) | ((u32)f2bf(a5 * inv) << 16);
    o.w = (u32)f2bf(a6 * inv) | ((u32)f2bf(a7 * inv) << 16);
    *(uint4*)(agg + (size_t)node * DH + c16 * 8) = o;
  }
}

// ---------------- fused GEMM (+optional second input) + bias + LN + ReLU ------
__global__ __launch_bounds__(256) void gemm_ln_relu(const u16* __restrict__ A1,
                                                    const u16* __restrict__ W1,
                                                    const u16* __restrict__ A2,
                                                    const u16* __restrict__ W2,
                                                    const float* __restrict__ bias,
                                                    const float* __restrict__ g,
                                                    const float* __restrict__ be,
                                                    u16* __restrict__ outh) {
  int lane = threadIdx.x & 63;
  int ntile = blockIdx.x * 4 + (threadIdx.x >> 6);
  if (ntile >= NTILES) return;
  int rA = lane & 15;       // A row within tile
  int ksel = lane >> 4;     // k sub-block 0..3
  int nodeA = ntile * 16 + rA;

  f32x4 acc[8];
  #pragma unroll
  for (int j = 0; j < 8; ++j) acc[j] = (f32x4){0.f,0.f,0.f,0.f};

  for (int pass = 0; pass < 2; ++pass) {
    const u16* A = pass ? A2 : A1;
    const u16* W = pass ? W2 : W1;
    if (!A) break;
    const u16* arow = A + (size_t)nodeA * DH + ksel * 8;
    const u16* wrow = W + (size_t)rA * DH + ksel * 8;
    #pragma unroll
    for (int ks = 0; ks < 4; ++ks) {
      bf16x8 af = *(const bf16x8*)(arow + ks * 32);
      #pragma unroll
      for (int jt = 0; jt < 8; ++jt) {
        bf16x8 bf = *(const bf16x8*)(wrow + ks * 32 + jt * 16 * DH);
        acc[jt] = __builtin_amdgcn_mfma_f32_16x16x32_bf16(af, bf, acc[jt], 0, 0, 0);
      }
    }
  }

  // epilogue: D[row=(lane>>4)*4+r][col=lane&15]
  int jcol = lane & 15;
  int rbase = (lane >> 4) * 4;
  float gv[8], bev[8];
  #pragma unroll
  for (int jt = 0; jt < 8; ++jt) {
    int j = jt * 16 + jcol;
    float bi = bias[j];
    gv[jt] = g[j]; bev[jt] = be[j];
    #pragma unroll
    for (int r = 0; r < 4; ++r) acc[jt][r] += bi;
  }
  #pragma unroll
  for (int r = 0; r < 4; ++r) {
    float s = 0.f;
    #pragma unroll
    for (int jt = 0; jt < 8; ++jt) s += acc[jt][r];
    s += __shfl_xor(s, 1); s += __shfl_xor(s, 2);
    s += __shfl_xor(s, 4); s += __shfl_xor(s, 8);
    float mean = s * (1.0f / 128.0f);
    float q = 0.f;
    #pragma unroll
    for (int jt = 0; jt < 8; ++jt) { float d = acc[jt][r] - mean; q += d * d; }
    q += __shfl_xor(q, 1); q += __shfl_xor(q, 2);
    q += __shfl_xor(q, 4); q += __shfl_xor(q, 8);
    float rs = rsqrtf(q * (1.0f / 128.0f) + 1e-5f);
    int node = ntile * 16 + rbase + r;
    u16* orow = outh + (size_t)node * DH + jcol;
    #pragma unroll
    for (int jt = 0; jt < 8; ++jt) {
      float y = (acc[jt][r] - mean) * rs * gv[jt] + bev[jt];
      y = fmaxf(y, 0.f);
      orow[jt * 16] = f2bf(y);
    }
  }
}

// ---------------- final linear + x-copy: out[n] = [x[n], h@lin_w.T + lin_b] ---
__global__ __launch_bounds__(256) void final_kernel(const u16* __restrict__ A,
                                                    const u16* __restrict__ W,
                                                    const float* __restrict__ bias,
                                                    const float* __restrict__ x,
                                                    float* __restrict__ out) {
  int lane = threadIdx.x & 63;
  int ntile = blockIdx.x * 4 + (threadIdx.x >> 6);
  if (ntile >= NTILES) return;
  int rA = lane & 15;
  int ksel = lane >> 4;
  int nodeA = ntile * 16 + rA;

  f32x4 acc[16];
  #pragma unroll
  for (int j = 0; j < 16; ++j) acc[j] = (f32x4){0.f,0.f,0.f,0.f};

  const u16* arow = A + (size_t)nodeA * DH + ksel * 8;
  const u16* wrow = W + (size_t)rA * DH + ksel * 8;
  #pragma unroll
  for (int ks = 0; ks < 4; ++ks) {
    bf16x8 af = *(const bf16x8*)(arow + ks * 32);
    #pragma unroll
    for (int jt = 0; jt < 16; ++jt) {
      bf16x8 bf = *(const bf16x8*)(wrow + ks * 32 + jt * 16 * DH);
      acc[jt] = __builtin_amdgcn_mfma_f32_16x16x32_bf16(af, bf, acc[jt], 0, 0, 0);
    }
  }

  int jcol = lane & 15;
  int rbase = (lane >> 4) * 4;
  float bv[16];
  #pragma unroll
  for (int jt = 0; jt < 16; ++jt) bv[jt] = bias[jt * 16 + jcol];
  #pragma unroll
  for (int r = 0; r < 4; ++r) {
    int node = ntile * 16 + rbase + r;
    float* orow = out + (size_t)node * 384 + 128 + jcol;
    #pragma unroll
    for (int jt = 0; jt < 16; ++jt) orow[jt * 16] = acc[jt][r] + bv[jt];
  }

  // copy x tile into out[:,0:128]: 16 rows x 32 float4 = 512 float4, 8 per lane
  int base = ntile * 16;
  #pragma unroll
  for (int t = 0; t < 8; ++t) {
    int idx = t * 64 + lane;
    int rr = idx >> 5;
    int cc = idx & 31;
    *(float4*)(out + (size_t)(base + rr) * 384 + cc * 4) =
        *(const float4*)(x + (size_t)(base + rr) * DH + cc * 4);
  }
}

extern "C" void kernel_launch(void* const* d_in, const int* in_sizes, int n_in,
                              void* d_out, int out_size, void* d_ws, size_t ws_size,
                              hipStream_t stream) {
  const float* x      = (const float*)d_in[0];
  const int*   ei     = (const int*)d_in[1];
  const float* pre_w  = (const float*)d_in[2];
  const float* pre_b  = (const float*)d_in[3];
  const float* pre_g  = (const float*)d_in[4];
  const float* pre_be = (const float*)d_in[5];
  const float* wl0    = (const float*)d_in[6];
  const float* wr0    = (const float*)d_in[7];
  const float* b0     = (const float*)d_in[8];
  const float* g0     = (const float*)d_in[9];
  const float* be0    = (const float*)d_in[10];
  const float* wl1    = (const float*)d_in[11];
  const float* wr1    = (const float*)d_in[12];
  const float* b1     = (const float*)d_in[13];
  const float* g1     = (const float*)d_in[14];
  const float* be1    = (const float*)d_in[15];
  const float* lin_w  = (const float*)d_in[16];
  const float* lin_b  = (const float*)d_in[17];
  float* out = (float*)d_out;

  char* ws = (char*)d_ws;
  size_t o = 0;
  auto alloc = [&](size_t bytes) { void* p = ws + o; o += (bytes + 255) & ~255ULL; return p; };
  u16* xb   = (u16*)alloc((size_t)NN * DH * 2);
  u16* hA   = (u16*)alloc((size_t)NN * DH * 2);
  u16* hB   = (u16*)alloc((size_t)NN * DH * 2);
  u16* aggb = (u16*)alloc((size_t)NN * DH * 2);
  u16* wb   = (u16*)alloc((size_t)114688 * 2);
  int* cnt     = (int*)alloc((size_t)NN * 4);
  int* off     = (int*)alloc((size_t)(NN + 1) * 4);
  int* fillpos = (int*)alloc((size_t)NN * 4);
  int* srcs    = (int*)alloc((size_t)NE * 4);
  int* partial = (int*)alloc((size_t)NBLK * 4);

  hipMemsetAsync(cnt, 0, (size_t)NN * 4, stream);

  {
    long total4 = ((long)NN * DH + 114688) / 4;
    int blocks = (int)((total4 + 255) / 256);
    cast_all<<<blocks, 256, 0, stream>>>(x, pre_w, wl0, wr0, wl1, wr1, lin_w, xb, wb);
  }
  count_kernel<<<NE / 256, 256, 0, stream>>>(ei, cnt);
  scan_part<<<NBLK, 256, 0, stream>>>(cnt, partial);
  scan_top<<<1, 256, 0, stream>>>(partial);
  scan_final<<<NBLK, 256, 0, stream>>>(cnt, partial, off, fillpos);
  fill_kernel<<<NE / 256, 256, 0, stream>>>(ei, fillpos, srcs);

  int gblocks = (NTILES + 3) / 4;   // 782
  // pre-MP layer
  gemm_ln_relu<<<gblocks, 256, 0, stream>>>(xb, wb + 0, nullptr, nullptr,
                                            pre_b, pre_g, pre_be, hA);
  // SAGE layer 0
  agg_kernel<<<NN / 4, 256, 0, stream>>>(hA, off, srcs, aggb);
  gemm_ln_relu<<<gblocks, 256, 0, stream>>>(aggb, wb + 16384, hA, wb + 32768,
                                            b0, g0, be0, hB);
  // SAGE layer 1
  agg_kernel<<<NN / 4, 256, 0, stream>>>(hB, off, srcs, aggb);
  gemm_ln_relu<<<gblocks, 256, 0, stream>>>(aggb, wb + 49152, hB, wb + 65536,
                                            b1, g1, be1, hA);
  // output (linear + x concat fused)
  final_kernel<<<gblocks, 256, 0, stream>>>(hA, wb + 81920, lin_b, x, out);
}

// Round 6
// 283.075 us; speedup vs baseline: 1.3928x; 1.0454x over previous
//
#include <hip/hip_runtime.h>
#include <hip/hip_bf16.h>

typedef unsigned short u16;
typedef unsigned int u32;
typedef __bf16 bf16x8 __attribute__((ext_vector_type(8)));
typedef float f32x4 __attribute__((ext_vector_type(4)));

#define NN 50000
#define NE 640000
#define DH 128
#define NTILES (NN / 16)        // 3125, exact
#define NBLK ((NN + 255) / 256) // 196 scan blocks

__device__ __forceinline__ u16 f2bf(float f) {
  u32 i = __float_as_uint(f);
  u32 r = (i + 0x7FFFu + ((i >> 16) & 1u)) >> 16;   // RNE
  return (u16)r;
}
__device__ __forceinline__ float bflo(u32 v) { return __uint_as_float(v << 16); }
__device__ __forceinline__ float bfhi(u32 v) { return __uint_as_float(v & 0xFFFF0000u); }

// ---------------- cast x + all weights fp32 -> bf16 (one launch) --------------
// wb layout (elements): pre_w@0, wl0@16384, wr0@32768, wl1@49152, wr1@65536, lin_w@81920
__global__ void cast_all(const float* __restrict__ x,
                         const float* __restrict__ pw, const float* __restrict__ wl0,
                         const float* __restrict__ wr0, const float* __restrict__ wl1,
                         const float* __restrict__ wr1, const float* __restrict__ lw,
                         u16* __restrict__ xb, u16* __restrict__ wb) {
  int idx = blockIdx.x * blockDim.x + threadIdx.x;
  long i4 = (long)idx * 4;
  const long XCNT = (long)NN * DH;      // 6,400,000
  const long WCNT = 114688;
  if (i4 < XCNT) {
    float4 v = *(const float4*)(x + i4);
    u32 a = (u32)f2bf(v.x) | ((u32)f2bf(v.y) << 16);
    u32 b = (u32)f2bf(v.z) | ((u32)f2bf(v.w) << 16);
    *(uint2*)(xb + i4) = make_uint2(a, b);
  } else if (i4 < XCNT + WCNT) {
    long w = i4 - XCNT;
    const float* src; long off;
    if (w < 16384)      { src = pw;  off = 0; }
    else if (w < 32768) { src = wl0; off = 16384; }
    else if (w < 49152) { src = wr0; off = 32768; }
    else if (w < 65536) { src = wl1; off = 49152; }
    else if (w < 81920) { src = wr1; off = 65536; }
    else                { src = lw;  off = 81920; }
    float4 v = *(const float4*)(src + (w - off));
    u32 a = (u32)f2bf(v.x) | ((u32)f2bf(v.y) << 16);
    u32 b = (u32)f2bf(v.z) | ((u32)f2bf(v.w) << 16);
    *(uint2*)(wb + w) = make_uint2(a, b);
  }
}

// ---------------- CSR build ----------------
__global__ void count_kernel(const int* __restrict__ ei, int* __restrict__ cnt) {
  int e = blockIdx.x * blockDim.x + threadIdx.x;
  if (e < NE) atomicAdd(&cnt[ei[NE + e]], 1);
}

__global__ __launch_bounds__(256) void scan_part(const int* __restrict__ cnt,
                                                 int* __restrict__ partial) {
  __shared__ int sm[4];
  int i = blockIdx.x * 256 + threadIdx.x;
  int s = (i < NN) ? cnt[i] : 0;
  s += __shfl_xor(s, 1);  s += __shfl_xor(s, 2);  s += __shfl_xor(s, 4);
  s += __shfl_xor(s, 8);  s += __shfl_xor(s, 16); s += __shfl_xor(s, 32);
  if ((threadIdx.x & 63) == 0) sm[threadIdx.x >> 6] = s;
  __syncthreads();
  if (threadIdx.x == 0) partial[blockIdx.x] = sm[0] + sm[1] + sm[2] + sm[3];
}

__global__ __launch_bounds__(256) void scan_top(int* __restrict__ partial) {
  __shared__ int sm[256];
  int tid = threadIdx.x;
  int v = (tid < NBLK) ? partial[tid] : 0;
  sm[tid] = v;
  __syncthreads();
  for (int d = 1; d < 256; d <<= 1) {
    int t = (tid >= d) ? sm[tid - d] : 0;
    __syncthreads();
    sm[tid] += t;
    __syncthreads();
  }
  if (tid < NBLK) partial[tid] = sm[tid] - v;   // exclusive prefix
}

__global__ __launch_bounds__(256) void scan_final(const int* __restrict__ cnt,
                                                  const int* __restrict__ partial,
                                                  int* __restrict__ off,
                                                  int* __restrict__ fillpos) {
  __shared__ int sm[256];
  int tid = threadIdx.x;
  int i = blockIdx.x * 256 + tid;
  int v = (i < NN) ? cnt[i] : 0;
  sm[tid] = v;
  __syncthreads();
  for (int d = 1; d < 256; d <<= 1) {
    int t = (tid >= d) ? sm[tid - d] : 0;
    __syncthreads();
    sm[tid] += t;
    __syncthreads();
  }
  int excl = sm[tid] - v + partial[blockIdx.x];
  if (i < NN) { off[i] = excl; fillpos[i] = excl; }
  if (i == 0) off[NN] = NE;
}

__global__ void fill_kernel(const int* __restrict__ ei, int* __restrict__ fillpos,
                            int* __restrict__ srcs) {
  int e = blockIdx.x * blockDim.x + threadIdx.x;
  if (e < NE) {
    int d = ei[NE + e];
    int p = atomicAdd(&fillpos[d], 1);
    srcs[p] = ei[e];
  }
}

// ---------------- mean aggregation: agg[i] = mean_{e: dst=i} h[src[e]] --------
__global__ __launch_bounds__(256) void agg_kernel(const u16* __restrict__ h,
                                                  const int* __restrict__ off,
                                                  const int* __restrict__ srcs,
                                                  u16* __restrict__ agg) {
  int node = blockIdx.x * 4 + (threadIdx.x >> 6);
  int lane = threadIdx.x & 63;
  int sub = lane >> 4;        // 0..3: which edge of the quad
  int c16 = lane & 15;        // which 16B chunk of the row
  int e0 = off[node], e1 = off[node + 1];
  float a0=0,a1=0,a2=0,a3=0,a4=0,a5=0,a6=0,a7=0;
  for (int e = e0 + sub; e < e1; e += 4) {
    int s = srcs[e];
    uint4 v = *(const uint4*)(h + (size_t)s * DH + c16 * 8);
    a0 += bflo(v.x); a1 += bfhi(v.x);
    a2 += bflo(v.y); a3 += bfhi(v.y);
    a4 += bflo(v.z); a5 += bfhi(v.z);
    a6 += bflo(v.w); a7 += bfhi(v.w);
  }
  a0 += __shfl_xor(a0,16); a0 += __shfl_xor(a0,32);
  a1 += __shfl_xor(a1,16); a1 += __shfl_xor(a1,32);
  a2 += __shfl_xor(a2,16); a2 += __shfl_xor(a2,32);
  a3 += __shfl_xor(a3,16); a3 += __shfl_xor(a3,32);
  a4 += __shfl_xor(a4,16); a4 += __shfl_xor(a4,32);
  a5 += __shfl_xor(a5,16); a5 += __shfl_xor(a5,32);
  a6 += __shfl_xor(a6,16); a6 += __shfl_xor(a6,32);
  a7 += __shfl_xor(a7,16); a7 += __shfl_xor(a7,32);
  int deg = e1 - e0;
  float inv = 1.0f / (float)(deg > 0 ? deg : 1);
  if (sub == 0) {
    uint4 o;
    o.x = (u32)f2bf(a0 * inv) | ((u32)f2bf(a1 * inv) << 16);
    o.y = (u32)f2bf(a2 * inv) | ((u32)f2bf(a3 * inv) << 16);
    o.z = (u32)f2bf(a4 * inv) | ((u32)f2bf(a5 * inv) << 16);
    o.w = (u32)f2bf(a6 * inv) | ((u32)f2bf(a7 * inv) << 16);
    *(uint4*)(agg + (size_t)node * DH + c16 * 8) = o;
  }
}

// ---------------- fused GEMM (+optional second input) + bias + LN + ReLU ------
// LDS-staged epilogue: per-wave transpose tile, then 256B-segment dwordx4 stores
__global__ __launch_bounds__(256) void gemm_ln_relu(const u16* __restrict__ A1,
                                                    const u16* __restrict__ W1,
                                                    const u16* __restrict__ A2,
                                                    const u16* __restrict__ W2,
                                                    const float* __restrict__ bias,
                                                    const float* __restrict__ g,
                                                    const float* __restrict__ be,
                                                    u16* __restrict__ outh) {
  __shared__ u16 st[4][16 * 136];   // 136 u16 row stride: 272B, 16B-aligned rows
  int lane = threadIdx.x & 63;
  int wid = threadIdx.x >> 6;
  int ntile = blockIdx.x * 4 + wid;
  if (ntile >= NTILES) return;
  u16* smw = st[wid];
  int rA = lane & 15;       // A row within tile
  int ksel = lane >> 4;     // k sub-block 0..3
  int nodeA = ntile * 16 + rA;

  f32x4 acc[8];
  #pragma unroll
  for (int j = 0; j < 8; ++j) acc[j] = (f32x4){0.f,0.f,0.f,0.f};

  for (int pass = 0; pass < 2; ++pass) {
    const u16* A = pass ? A2 : A1;
    const u16* W = pass ? W2 : W1;
    if (!A) break;
    const u16* arow = A + (size_t)nodeA * DH + ksel * 8;
    const u16* wrow = W + (size_t)rA * DH + ksel * 8;
    #pragma unroll
    for (int ks = 0; ks < 4; ++ks) {
      bf16x8 af = *(const bf16x8*)(arow + ks * 32);
      #pragma unroll
      for (int jt = 0; jt < 8; ++jt) {
        bf16x8 bf = *(const bf16x8*)(wrow + ks * 32 + jt * 16 * DH);
        acc[jt] = __builtin_amdgcn_mfma_f32_16x16x32_bf16(af, bf, acc[jt], 0, 0, 0);
      }
    }
  }

  // epilogue: D[row=(lane>>4)*4+r][col=lane&15]
  int jcol = lane & 15;
  int rbase = (lane >> 4) * 4;
  float gv[8], bev[8];
  #pragma unroll
  for (int jt = 0; jt < 8; ++jt) {
    int j = jt * 16 + jcol;
    float bi = bias[j];
    gv[jt] = g[j]; bev[jt] = be[j];
    #pragma unroll
    for (int r = 0; r < 4; ++r) acc[jt][r] += bi;
  }
  #pragma unroll
  for (int r = 0; r < 4; ++r) {
    float s = 0.f;
    #pragma unroll
    for (int jt = 0; jt < 8; ++jt) s += acc[jt][r];
    s += __shfl_xor(s, 1); s += __shfl_xor(s, 2);
    s += __shfl_xor(s, 4); s += __shfl_xor(s, 8);
    float mean = s * (1.0f / 128.0f);
    float q = 0.f;
    #pragma unroll
    for (int jt = 0; jt < 8; ++jt) { float d = acc[jt][r] - mean; q += d * d; }
    q += __shfl_xor(q, 1); q += __shfl_xor(q, 2);
    q += __shfl_xor(q, 4); q += __shfl_xor(q, 8);
    float rs = rsqrtf(q * (1.0f / 128.0f) + 1e-5f);
    #pragma unroll
    for (int jt = 0; jt < 8; ++jt) {
      float y = (acc[jt][r] - mean) * rs * gv[jt] + bev[jt];
      y = fmaxf(y, 0.f);
      smw[(rbase + r) * 136 + jt * 16 + jcol] = f2bf(y);
    }
  }
  // readback: 4 insts, each = 4 rows x 256B contiguous segments
  int tbase = ntile * 16;
  #pragma unroll
  for (int t = 0; t < 4; ++t) {
    int idx = t * 64 + lane;
    int row = idx >> 4;
    int c = idx & 15;
    uint4 v = *(const uint4*)&smw[row * 136 + c * 8];
    *(uint4*)(outh + (size_t)(tbase + row) * DH + c * 8) = v;
  }
}

// ---------------- final linear + x-copy: out[n] = [x[n], h@lin_w.T + lin_b] ---
// LDS-staged: full-row coalesced f32x4 nontemporal stores
__global__ __launch_bounds__(128) void final_kernel(const u16* __restrict__ A,
                                                    const u16* __restrict__ W,
                                                    const float* __restrict__ bias,
                                                    const float* __restrict__ x,
                                                    float* __restrict__ out) {
  __shared__ float sm[2][16 * 260];   // 260-float row stride: 2-way bank alias max
  int lane = threadIdx.x & 63;
  int wid = threadIdx.x >> 6;
  int ntile = blockIdx.x * 2 + wid;
  if (ntile >= NTILES) return;
  float* smw = sm[wid];
  int rA = lane & 15;
  int ksel = lane >> 4;
  int nodeA = ntile * 16 + rA;

  f32x4 acc[16];
  #pragma unroll
  for (int j = 0; j < 16; ++j) acc[j] = (f32x4){0.f,0.f,0.f,0.f};

  const u16* arow = A + (size_t)nodeA * DH + ksel * 8;
  const u16* wrow = W + (size_t)rA * DH + ksel * 8;
  #pragma unroll
  for (int ks = 0; ks < 4; ++ks) {
    bf16x8 af = *(const bf16x8*)(arow + ks * 32);
    #pragma unroll
    for (int jt = 0; jt < 16; ++jt) {
      bf16x8 bf = *(const bf16x8*)(wrow + ks * 32 + jt * 16 * DH);
      acc[jt] = __builtin_amdgcn_mfma_f32_16x16x32_bf16(af, bf, acc[jt], 0, 0, 0);
    }
  }

  int jcol = lane & 15;
  int rbase = (lane >> 4) * 4;
  #pragma unroll
  for (int jt = 0; jt < 16; ++jt) {
    float bv = bias[jt * 16 + jcol];
    #pragma unroll
    for (int r = 0; r < 4; ++r)
      smw[(rbase + r) * 260 + jt * 16 + jcol] = acc[jt][r] + bv;
  }

  int base = ntile * 16;
  // x -> out[:,0:128]: 8 insts, each 2 rows x 512B segments
  #pragma unroll
  for (int t = 0; t < 8; ++t) {
    int idx = t * 64 + lane;
    int rr = idx >> 5;
    int cc = idx & 31;
    f32x4 v = *(const f32x4*)(x + (size_t)(base + rr) * DH + cc * 4);
    __builtin_nontemporal_store(v, (f32x4*)(out + (size_t)(base + rr) * 384 + cc * 4));
  }
  // linear part -> out[:,128:384]: 16 insts, each one full 1KB contiguous row
  #pragma unroll
  for (int t = 0; t < 16; ++t) {
    f32x4 v = *(const f32x4*)&smw[t * 260 + lane * 4];
    __builtin_nontemporal_store(v, (f32x4*)(out + (size_t)(base + t) * 384 + 128 + lane * 4));
  }
}

extern "C" void kernel_launch(void* const* d_in, const int* in_sizes, int n_in,
                              void* d_out, int out_size, void* d_ws, size_t ws_size,
                              hipStream_t stream) {
  const float* x      = (const float*)d_in[0];
  const int*   ei     = (const int*)d_in[1];
  const float* pre_w  = (const float*)d_in[2];
  const float* pre_b  = (const float*)d_in[3];
  const float* pre_g  = (const float*)d_in[4];
  const float* pre_be = (const float*)d_in[5];
  const float* wl0    = (const float*)d_in[6];
  const float* wr0    = (const float*)d_in[7];
  const float* b0     = (const float*)d_in[8];
  const float* g0     = (const float*)d_in[9];
  const float* be0    = (const float*)d_in[10];
  const float* wl1    = (const float*)d_in[11];
  const float* wr1    = (const float*)d_in[12];
  const float* b1     = (const float*)d_in[13];
  const float* g1     = (const float*)d_in[14];
  const float* be1    = (const float*)d_in[15];
  const float* lin_w  = (const float*)d_in[16];
  const float* lin_b  = (const float*)d_in[17];
  float* out = (float*)d_out;

  char* ws = (char*)d_ws;
  size_t o = 0;
  auto alloc = [&](size_t bytes) { void* p = ws + o; o += (bytes + 255) & ~255ULL; return p; };
  u16* xb   = (u16*)alloc((size_t)NN * DH * 2);
  u16* hA   = (u16*)alloc((size_t)NN * DH * 2);
  u16* hB   = (u16*)alloc((size_t)NN * DH * 2);
  u16* aggb = (u16*)alloc((size_t)NN * DH * 2);
  u16* wb   = (u16*)alloc((size_t)114688 * 2);
  int* cnt     = (int*)alloc((size_t)NN * 4);
  int* off     = (int*)alloc((size_t)(NN + 1) * 4);
  int* fillpos = (int*)alloc((size_t)NN * 4);
  int* srcs    = (int*)alloc((size_t)NE * 4);
  int* partial = (int*)alloc((size_t)NBLK * 4);

  (void)hipMemsetAsync(cnt, 0, (size_t)NN * 4, stream);

  {
    long total4 = ((long)NN * DH + 114688) / 4;
    int blocks = (int)((total4 + 255) / 256);
    cast_all<<<blocks, 256, 0, stream>>>(x, pre_w, wl0, wr0, wl1, wr1, lin_w, xb, wb);
  }
  count_kernel<<<NE / 256, 256, 0, stream>>>(ei, cnt);
  scan_part<<<NBLK, 256, 0, stream>>>(cnt, partial);
  scan_top<<<1, 256, 0, stream>>>(partial);
  scan_final<<<NBLK, 256, 0, stream>>>(cnt, partial, off, fillpos);
  fill_kernel<<<NE / 256, 256, 0, stream>>>(ei, fillpos, srcs);

  int gblocks = (NTILES + 3) / 4;   // 782
  // pre-MP layer
  gemm_ln_relu<<<gblocks, 256, 0, stream>>>(xb, wb + 0, nullptr, nullptr,
                                            pre_b, pre_g, pre_be, hA);
  // SAGE layer 0
  agg_kernel<<<NN / 4, 256, 0, stream>>>(hA, off, srcs, aggb);
  gemm_ln_relu<<<gblocks, 256, 0, stream>>>(aggb, wb + 16384, hA, wb + 32768,
                                            b0, g0, be0, hB);
  // SAGE layer 1
  agg_kernel<<<NN / 4, 256, 0, stream>>>(hB, off, srcs, aggb);
  gemm_ln_relu<<<gblocks, 256, 0, stream>>>(aggb, wb + 49152, hB, wb + 65536,
                                            b1, g1, be1, hA);
  // output (linear + x concat fused)
  final_kernel<<<(NTILES + 1) / 2, 128, 0, stream>>>(hA, wb + 81920, lin_b, x, out);
}